// Round 1
// baseline (571.917 us; speedup 1.0000x reference)
//
#include <hip/hip_runtime.h>
#include <stdint.h>

#define OUT_F 4096
#define IN_F  4096
#define MROWS 8192   // 4*2048

typedef __attribute__((ext_vector_type(8))) short  shortx8;   // 8 bf16 = 4 VGPRs
typedef __attribute__((ext_vector_type(4))) float  floatx4;

// fp32 -> bf16 bits, round-to-nearest-even (no NaN special-case needed here)
__device__ __forceinline__ unsigned short f32_to_bf16(float f) {
    unsigned int u = __builtin_bit_cast(unsigned int, f);
    u += 0x7FFFu + ((u >> 16) & 1u);
    return (unsigned short)(u >> 16);
}

// async global->LDS, 16B per lane. LDS dest = wave-uniform base + lane*16.
__device__ __forceinline__ void gload_lds16(const void* gsrc, void* ldst) {
    __builtin_amdgcn_global_load_lds(
        (const __attribute__((address_space(1))) uint32_t*)gsrc,
        (__attribute__((address_space(3))) uint32_t*)ldst,
        16, 0, 0);
}

// ---------------- kernel 1: x fp32 -> bf16 ----------------
__global__ void __launch_bounds__(256) cast_x_kernel(const float* __restrict__ x,
                                                     short* __restrict__ xb) {
    int64_t i = ((int64_t)blockIdx.x * 256 + threadIdx.x) * 8;
    float4 v0 = *(const float4*)(x + i);
    float4 v1 = *(const float4*)(x + i + 4);
    shortx8 o;
    o[0] = (short)f32_to_bf16(v0.x); o[1] = (short)f32_to_bf16(v0.y);
    o[2] = (short)f32_to_bf16(v0.z); o[3] = (short)f32_to_bf16(v0.w);
    o[4] = (short)f32_to_bf16(v1.x); o[5] = (short)f32_to_bf16(v1.y);
    o[6] = (short)f32_to_bf16(v1.z); o[7] = (short)f32_to_bf16(v1.w);
    *(shortx8*)(xb + i) = o;
}

// ---------------- kernel 2: dequant int8(int32) * block-scale -> bf16 ----------------
__global__ void __launch_bounds__(256) dequant_w_kernel(const int* __restrict__ q,
                                                        const float* __restrict__ s,
                                                        short* __restrict__ wb) {
    int64_t i = ((int64_t)blockIdx.x * 256 + threadIdx.x) * 8;
    float sc = s[i >> 6];              // 8 elems always within one 64-block
    int4 a = *(const int4*)(q + i);
    int4 b = *(const int4*)(q + i + 4);
    shortx8 o;
    o[0] = (short)f32_to_bf16((float)a.x * sc); o[1] = (short)f32_to_bf16((float)a.y * sc);
    o[2] = (short)f32_to_bf16((float)a.z * sc); o[3] = (short)f32_to_bf16((float)a.w * sc);
    o[4] = (short)f32_to_bf16((float)b.x * sc); o[5] = (short)f32_to_bf16((float)b.y * sc);
    o[6] = (short)f32_to_bf16((float)b.z * sc); o[7] = (short)f32_to_bf16((float)b.w * sc);
    *(shortx8*)(wb + i) = o;
}

// ---------------- kernel 3: bf16 GEMM  C[M,N] = A[M,K] * B[N,K]^T + bias ----------------
// m97 structure: 128x128 block tile, BK=32, 256 threads = 4 waves (2x2),
// each wave 64x64 = 4x4 tiles of v_mfma_f32_16x16x32_bf16,
// global_load_lds width=16 staging, single-buffered 2-barrier K-loop.
__global__ void __launch_bounds__(256)
gemm_bf16_kernel(const short* __restrict__ A, const short* __restrict__ B,
                 const float* __restrict__ bias, float* __restrict__ C) {
    __shared__ short sA[128 * 32];   // 8 KB, row-major, row stride 32 (no pad: global_load_lds)
    __shared__ short sB[128 * 32];   // 8 KB

    const int tid  = threadIdx.x;
    const int wave = tid >> 6;       // 0..3
    const int lane = tid & 63;
    const int wr   = wave >> 1;      // 0..1  (wave row in 2x2 grid)
    const int wc   = wave & 1;       // 0..1

    const int row0 = blockIdx.y * 128;   // M offset
    const int col0 = blockIdx.x * 128;   // N offset

    // staging: wave handles segments {wave*2, wave*2+1}, each = 16 rows x 32 cols
    // lane i -> row seg*16 + i/4, col (i%4)*8   (matches HW lds dest base+lane*16)
    const int lr = lane >> 2;
    const int lc = (lane & 3) * 8;
    const short* gA = A + (int64_t)(row0 + wave * 32 + lr) * IN_F + lc;
    const short* gB = B + (int64_t)(col0 + wave * 32 + lr) * IN_F + lc;
    short* lA = sA + wave * 1024;    // wave-uniform LDS base (elements); +512 for seg t=1
    short* lB = sB + wave * 1024;

    floatx4 acc[4][4];
#pragma unroll
    for (int i = 0; i < 4; i++)
#pragma unroll
        for (int j = 0; j < 4; j++) acc[i][j] = (floatx4)(0.0f);

    const int m_lane = lane & 15;          // A: m index / B: n index
    const int k_off  = (lane >> 4) * 8;    // k offset within BK=32

    for (int k0 = 0; k0 < IN_F; k0 += 32) {
        gload_lds16(gA,              lA);
        gload_lds16(gA + 16 * IN_F,  lA + 512);
        gload_lds16(gB,              lB);
        gload_lds16(gB + 16 * IN_F,  lB + 512);
        gA += 32; gB += 32;
        __syncthreads();   // compiler drains vmcnt(0): LDS tiles complete

        shortx8 af[4], bfr[4];
#pragma unroll
        for (int mt = 0; mt < 4; mt++)
            af[mt] = *(const shortx8*)&sA[(wr * 64 + mt * 16 + m_lane) * 32 + k_off];
#pragma unroll
        for (int nt = 0; nt < 4; nt++)
            bfr[nt] = *(const shortx8*)&sB[(wc * 64 + nt * 16 + m_lane) * 32 + k_off];
#pragma unroll
        for (int mt = 0; mt < 4; mt++)
#pragma unroll
            for (int nt = 0; nt < 4; nt++)
                acc[mt][nt] = __builtin_amdgcn_mfma_f32_16x16x32_bf16(
                    af[mt], bfr[nt], acc[mt][nt], 0, 0, 0);
        __syncthreads();   // all waves done reading before next overwrite
    }

    // epilogue: C/D layout col = lane&15, row = (lane>>4)*4 + reg  [m89/m91 verified]
    const int quad = lane >> 4;
    const int out_r_base = row0 + wr * 64;
    const int out_c_base = col0 + wc * 64;
#pragma unroll
    for (int nt = 0; nt < 4; nt++) {
        const int gcol = out_c_base + nt * 16 + m_lane;
        const float bv = bias[gcol];
#pragma unroll
        for (int mt = 0; mt < 4; mt++) {
            const int grow = out_r_base + mt * 16 + quad * 4;
            float* outp = C + (int64_t)grow * OUT_F + gcol;
#pragma unroll
            for (int r = 0; r < 4; r++)
                outp[(int64_t)r * OUT_F] = acc[mt][nt][r] + bv;
        }
    }
}

extern "C" void kernel_launch(void* const* d_in, const int* in_sizes, int n_in,
                              void* d_out, int out_size, void* d_ws, size_t ws_size,
                              hipStream_t stream) {
    const float* x    = (const float*)d_in[0];
    const int*   qw   = (const int*)d_in[1];
    const float* sc   = (const float*)d_in[2];
    const float* bias = (const float*)d_in[3];
    float*       out  = (float*)d_out;

    // workspace layout: [x_bf16: 8192*4096*2 = 64 MiB][w_bf16: 4096*4096*2 = 32 MiB]
    short* xb = (short*)d_ws;
    short* wb = (short*)((char*)d_ws + (size_t)MROWS * IN_F * sizeof(short));

    cast_x_kernel<<<(MROWS * IN_F) / 8 / 256, 256, 0, stream>>>(x, xb);
    dequant_w_kernel<<<(OUT_F * IN_F) / 8 / 256, 256, 0, stream>>>(qw, sc, wb);

    dim3 grid(OUT_F / 128, MROWS / 128);   // (32, 64) = 2048 blocks
    gemm_bf16_kernel<<<grid, 256, 0, stream>>>(xb, wb, bias, out);
}

// Round 2
// 562.258 us; speedup vs baseline: 1.0172x; 1.0172x over previous
//
#include <hip/hip_runtime.h>
#include <stdint.h>

#define OUT_F 4096
#define IN_F  4096
#define MROWS 8192   // 4*2048

typedef __attribute__((ext_vector_type(8))) short  shortx8;   // 8 bf16 = 4 VGPRs
typedef __attribute__((ext_vector_type(4))) float  floatx4;

// fp32 -> bf16 bits, round-to-nearest-even
__device__ __forceinline__ unsigned short f32_to_bf16(float f) {
    unsigned int u = __builtin_bit_cast(unsigned int, f);
    u += 0x7FFFu + ((u >> 16) & 1u);
    return (unsigned short)(u >> 16);
}

// async global->LDS, 16B per lane. LDS dest = wave-uniform base + lane*16.
__device__ __forceinline__ void gload_lds16(const void* gsrc, void* ldst) {
    __builtin_amdgcn_global_load_lds(
        (const __attribute__((address_space(1))) uint32_t*)gsrc,
        (__attribute__((address_space(3))) uint32_t*)ldst,
        16, 0, 0);
}

// ---------------- fused preprocessing: x fp32->bf16  +  dequant W ----------------
// blocks [0, 16384): cast x (33.55M elems, 8/thread)
// blocks [16384, 24576): dequant qweight (16.78M elems, 8/thread)
// Fused so the two independent streams run concurrently across CUs.
#define CAST_BLOCKS 16384
__global__ void __launch_bounds__(256)
preprocess_kernel(const float* __restrict__ x, short* __restrict__ xb,
                  const int* __restrict__ q, const float* __restrict__ s,
                  short* __restrict__ wb) {
    const int b = blockIdx.x;
    if (b < CAST_BLOCKS) {
        int64_t i = ((int64_t)b * 256 + threadIdx.x) * 8;
        float4 v0 = *(const float4*)(x + i);
        float4 v1 = *(const float4*)(x + i + 4);
        shortx8 o;
        o[0] = (short)f32_to_bf16(v0.x); o[1] = (short)f32_to_bf16(v0.y);
        o[2] = (short)f32_to_bf16(v0.z); o[3] = (short)f32_to_bf16(v0.w);
        o[4] = (short)f32_to_bf16(v1.x); o[5] = (short)f32_to_bf16(v1.y);
        o[6] = (short)f32_to_bf16(v1.z); o[7] = (short)f32_to_bf16(v1.w);
        *(shortx8*)(xb + i) = o;
    } else {
        int64_t i = ((int64_t)(b - CAST_BLOCKS) * 256 + threadIdx.x) * 8;
        float sc = s[i >> 6];              // 8 elems always within one 64-block
        int4 a = *(const int4*)(q + i);
        int4 c = *(const int4*)(q + i + 4);
        shortx8 o;
        o[0] = (short)f32_to_bf16((float)a.x * sc); o[1] = (short)f32_to_bf16((float)a.y * sc);
        o[2] = (short)f32_to_bf16((float)a.z * sc); o[3] = (short)f32_to_bf16((float)a.w * sc);
        o[4] = (short)f32_to_bf16((float)c.x * sc); o[5] = (short)f32_to_bf16((float)c.y * sc);
        o[6] = (short)f32_to_bf16((float)c.z * sc); o[7] = (short)f32_to_bf16((float)c.w * sc);
        *(shortx8*)(wb + i) = o;
    }
}

// ---------------- bf16 GEMM  C[M,N] = A[M,K] * B[N,K]^T + bias ----------------
// m97 structure + XOR bank-conflict swizzle:
// LDS position of the 16B chunk (row, kblk) is  pos = kblk ^ ((row>>1)&3).
// Per 16-lane ds_read_b128 phase, the 64 bank accesses cover all 32 banks
// exactly 2x (2-way is free, m136) instead of the unswizzled 8-per-bank-quad.
__global__ void __launch_bounds__(256)
gemm_bf16_kernel(const short* __restrict__ A, const short* __restrict__ B,
                 const float* __restrict__ bias, float* __restrict__ C) {
    __shared__ short sA[128 * 32];   // 8 KB, row stride 32 shorts (64 B)
    __shared__ short sB[128 * 32];   // 8 KB

    const int tid  = threadIdx.x;
    const int wave = tid >> 6;       // 0..3
    const int lane = tid & 63;
    const int wr   = wave >> 1;      // 0..1
    const int wc   = wave & 1;       // 0..1

    const int row0 = blockIdx.y * 128;   // M offset
    const int col0 = blockIdx.x * 128;   // N offset

    // staging: lane's LDS slot is (row = lane>>2, pos = lane&3); it must hold
    // global chunk kblk = pos ^ ((row>>1)&3)  (swizzle is seg-base invariant
    // since segment bases are multiples of 16).
    const int lr = lane >> 2;
    const int lc = ((lane & 3) ^ ((lr >> 1) & 3)) * 8;
    const short* gA = A + (int64_t)(row0 + wave * 32 + lr) * IN_F + lc;
    const short* gB = B + (int64_t)(col0 + wave * 32 + lr) * IN_F + lc;
    short* lA = sA + wave * 1024;    // wave-uniform LDS base; +512 for 2nd 16-row seg
    short* lB = sB + wave * 1024;

    floatx4 acc[4][4];
#pragma unroll
    for (int i = 0; i < 4; i++)
#pragma unroll
        for (int j = 0; j < 4; j++) acc[i][j] = (floatx4)(0.0f);

    const int m_lane = lane & 15;          // A: m index / B: n index
    // read-side swizzle: row = (multiple of 16) + m_lane, so (row>>1)&3 = (m_lane>>1)&3
    const int kpos = (((lane >> 4) ^ ((m_lane >> 1) & 3))) * 8;

    for (int k0 = 0; k0 < IN_F; k0 += 32) {
        gload_lds16(gA,              lA);
        gload_lds16(gA + 16 * IN_F,  lA + 512);
        gload_lds16(gB,              lB);
        gload_lds16(gB + 16 * IN_F,  lB + 512);
        gA += 32; gB += 32;
        __syncthreads();   // drains vmcnt(0): LDS tiles complete

        shortx8 af[4], bfr[4];
#pragma unroll
        for (int mt = 0; mt < 4; mt++)
            af[mt] = *(const shortx8*)&sA[(wr * 64 + mt * 16 + m_lane) * 32 + kpos];
#pragma unroll
        for (int nt = 0; nt < 4; nt++)
            bfr[nt] = *(const shortx8*)&sB[(wc * 64 + nt * 16 + m_lane) * 32 + kpos];
#pragma unroll
        for (int mt = 0; mt < 4; mt++)
#pragma unroll
            for (int nt = 0; nt < 4; nt++)
                acc[mt][nt] = __builtin_amdgcn_mfma_f32_16x16x32_bf16(
                    af[mt], bfr[nt], acc[mt][nt], 0, 0, 0);
        __syncthreads();   // all waves done reading before next overwrite
    }

    // epilogue: C/D layout col = lane&15, row = (lane>>4)*4 + reg  [m89/m91]
    const int quad = lane >> 4;
    const int out_r_base = row0 + wr * 64;
    const int out_c_base = col0 + wc * 64;
#pragma unroll
    for (int nt = 0; nt < 4; nt++) {
        const int gcol = out_c_base + nt * 16 + m_lane;
        const float bv = bias[gcol];
#pragma unroll
        for (int mt = 0; mt < 4; mt++) {
            const int grow = out_r_base + mt * 16 + quad * 4;
            float* outp = C + (int64_t)grow * OUT_F + gcol;
#pragma unroll
            for (int r = 0; r < 4; r++)
                outp[(int64_t)r * OUT_F] = acc[mt][nt][r] + bv;
        }
    }
}

extern "C" void kernel_launch(void* const* d_in, const int* in_sizes, int n_in,
                              void* d_out, int out_size, void* d_ws, size_t ws_size,
                              hipStream_t stream) {
    const float* x    = (const float*)d_in[0];
    const int*   qw   = (const int*)d_in[1];
    const float* sc   = (const float*)d_in[2];
    const float* bias = (const float*)d_in[3];
    float*       out  = (float*)d_out;

    // workspace: [x_bf16: 64 MiB][w_bf16: 32 MiB]
    short* xb = (short*)d_ws;
    short* wb = (short*)((char*)d_ws + (size_t)MROWS * IN_F * sizeof(short));

    preprocess_kernel<<<CAST_BLOCKS + (OUT_F * IN_F) / 8 / 256, 256, 0, stream>>>(
        x, xb, qw, sc, wb);

    dim3 grid(OUT_F / 128, MROWS / 128);   // (32, 64) = 2048 blocks
    gemm_bf16_kernel<<<grid, 256, 0, stream>>>(xb, wb, bias, out);
}